// Round 1
// baseline (530.394 us; speedup 1.0000x reference)
//
#include <hip/hip_runtime.h>

#define NN 50000
#define NE 800000
#define H  64

// ---------- degree ----------
__global__ __launch_bounds__(256) void k_deg_init(float* __restrict__ deg) {
  int i = blockIdx.x * 256 + threadIdx.x;
  if (i < NN) deg[i] = 1.0f;  // self-loop
}

__global__ __launch_bounds__(256) void k_deg(const int* __restrict__ ei,
                                             float* __restrict__ deg) {
  int e = blockIdx.x * 256 + threadIdx.x;
  if (e < NE) atomicAdd(&deg[ei[NE + e]], 1.0f);  // in-degree on dst
}

// ---------- node encoder + h0@W_gcn + dinv + hg init (self-loop + bias) ----------
__global__ __launch_bounds__(256) void k_node(
    const float* __restrict__ x, const float* __restrict__ W_ne,
    const float* __restrict__ b_ne, const float* __restrict__ W_gcn,
    const float* __restrict__ b_gcn, const float* __restrict__ deg,
    float* __restrict__ dinv, float* __restrict__ ht, float* __restrict__ hg) {
  __shared__ float sh[4][H];
  const int lane = threadIdx.x & 63;
  const int wv   = threadIdx.x >> 6;
  const int n    = blockIdx.x * 4 + wv;  // NN % 4 == 0, grid exact

  float acc = b_ne[lane];
#pragma unroll
  for (int k = 0; k < 5; ++k) acc = fmaf(x[n * 5 + k], W_ne[k * H + lane], acc);
  acc = fmaxf(acc, 0.0f);
  sh[wv][lane] = acc;
  __syncthreads();

  float hv = 0.0f;
#pragma unroll 8
  for (int k = 0; k < H; ++k) hv = fmaf(sh[wv][k], W_gcn[k * H + lane], hv);

  const float dv = rsqrtf(deg[n]);  // deg >= 1 always
  if (lane == 0) dinv[n] = dv;
  ht[n * H + lane] = hv;
  hg[n * H + lane] = fmaf(hv, dv * dv, b_gcn[lane]);  // self-loop + bias
}

// ---------- edge scatter: hg[dst] += ht[src] * dinv[src]*dinv[dst] ----------
__global__ __launch_bounds__(256) void k_scatter(const int* __restrict__ ei,
                                                 const float* __restrict__ dinv,
                                                 const float* __restrict__ ht,
                                                 float* __restrict__ hg) {
  const int lane = threadIdx.x & 63;
  const int wv   = threadIdx.x >> 6;
  const int e    = blockIdx.x * 4 + wv;  // NE % 4 == 0, grid exact
  const int s = ei[e], d = ei[NE + e];
  const float nv = dinv[s] * dinv[d];
  atomicAdd(&hg[d * H + lane], ht[s * H + lane] * nv);
}

// ---------- fused edge MLP: relu([hg[s],hg[d],ef] @ W1 + b1) @ W2 + b2 ----------
__global__ __launch_bounds__(256) void k_mlp(
    const int* __restrict__ ei, const float* __restrict__ eattr,
    const float* __restrict__ hg, const float* __restrict__ W_ee,
    const float* __restrict__ b_ee, const float* __restrict__ W1,
    const float* __restrict__ b1, const float* __restrict__ W2,
    const float* __restrict__ b2, float* __restrict__ out) {
  const int e = blockIdx.x * 256 + threadIdx.x;  // NE % 256 == 0
  const int s = ei[e], d = ei[NE + e];
  const float ea = eattr[e];

  float z[H];
#pragma unroll
  for (int h = 0; h < H; ++h) z[h] = b1[h];

  // phase A: k = 0..63  (hg[src] block of W1)
  {
    const float4* __restrict__ ps = (const float4*)(hg + (size_t)s * H);
#pragma unroll 1
    for (int q = 0; q < 16; ++q) {
      const float4 v = ps[q];
      const float* __restrict__ wr = W1 + (q * 4) * H;
#pragma unroll
      for (int h = 0; h < H; ++h) {
        z[h] = fmaf(v.x, wr[h], z[h]);
        z[h] = fmaf(v.y, wr[H + h], z[h]);
        z[h] = fmaf(v.z, wr[2 * H + h], z[h]);
        z[h] = fmaf(v.w, wr[3 * H + h], z[h]);
      }
    }
  }
  // phase B: k = 64..127 (hg[dst] block of W1)
  {
    const float4* __restrict__ pd = (const float4*)(hg + (size_t)d * H);
#pragma unroll 1
    for (int q = 0; q < 16; ++q) {
      const float4 v = pd[q];
      const float* __restrict__ wr = W1 + (64 + q * 4) * H;
#pragma unroll
      for (int h = 0; h < H; ++h) {
        z[h] = fmaf(v.x, wr[h], z[h]);
        z[h] = fmaf(v.y, wr[H + h], z[h]);
        z[h] = fmaf(v.z, wr[2 * H + h], z[h]);
        z[h] = fmaf(v.w, wr[3 * H + h], z[h]);
      }
    }
  }
  // phase C: k = 128..191 (edge feature block; ef computed on the fly)
  {
#pragma unroll 1
    for (int k = 0; k < H; ++k) {
      const float efk = fmaxf(fmaf(ea, W_ee[k], b_ee[k]), 0.0f);
      const float* __restrict__ wr = W1 + (128 + k) * H;
#pragma unroll
      for (int h = 0; h < H; ++h) z[h] = fmaf(efk, wr[h], z[h]);
    }
  }

  float o = b2[0];
#pragma unroll
  for (int h = 0; h < H; ++h) o = fmaf(fmaxf(z[h], 0.0f), W2[h], o);
  out[e] = o;
}

extern "C" void kernel_launch(void* const* d_in, const int* in_sizes, int n_in,
                              void* d_out, int out_size, void* d_ws, size_t ws_size,
                              hipStream_t stream) {
  const float* x     = (const float*)d_in[0];
  const int*   ei    = (const int*)d_in[1];
  const float* eattr = (const float*)d_in[2];
  const float* W_ne  = (const float*)d_in[3];
  const float* b_ne  = (const float*)d_in[4];
  const float* W_ee  = (const float*)d_in[5];
  const float* b_ee  = (const float*)d_in[6];
  const float* W_gcn = (const float*)d_in[7];
  const float* b_gcn = (const float*)d_in[8];
  const float* W1    = (const float*)d_in[9];
  const float* b1    = (const float*)d_in[10];
  const float* W2    = (const float*)d_in[11];
  const float* b2    = (const float*)d_in[12];
  float* out = (float*)d_out;

  float* ws   = (float*)d_ws;
  float* ht   = ws;                 // NN*H floats
  float* hg   = ws + (size_t)NN * H;  // NN*H floats
  float* deg  = ws + (size_t)2 * NN * H;  // NN floats
  float* dinv = deg + NN;           // NN floats

  k_deg_init<<<(NN + 255) / 256, 256, 0, stream>>>(deg);
  k_deg<<<NE / 256, 256, 0, stream>>>(ei, deg);
  k_node<<<NN / 4, 256, 0, stream>>>(x, W_ne, b_ne, W_gcn, b_gcn, deg, dinv, ht, hg);
  k_scatter<<<NE / 4, 256, 0, stream>>>(ei, dinv, ht, hg);
  k_mlp<<<NE / 256, 256, 0, stream>>>(ei, eattr, hg, W_ee, b_ee, W1, b1, W2, b2, out);
}

// Round 2
// 325.606 us; speedup vs baseline: 1.6289x; 1.6289x over previous
//
#include <hip/hip_runtime.h>

#define NN 50000
#define NE 800000
#define H  64

typedef __attribute__((ext_vector_type(8))) short bf16x8;
typedef __attribute__((ext_vector_type(4))) float f32x4;

__device__ __forceinline__ unsigned short f2bf(float f) {
  unsigned int u = __builtin_bit_cast(unsigned int, f);
  u += 0x7FFFu + ((u >> 16) & 1u);  // RNE
  return (unsigned short)(u >> 16);
}

// ---------- degree ----------
__global__ __launch_bounds__(256) void k_deg_init(float* __restrict__ deg) {
  int i = blockIdx.x * 256 + threadIdx.x;
  if (i < NN) deg[i] = 1.0f;  // self-loop
}

__global__ __launch_bounds__(256) void k_deg(const int* __restrict__ ei,
                                             float* __restrict__ deg) {
  int e = blockIdx.x * 256 + threadIdx.x;
  if (e < NE) atomicAdd(&deg[ei[NE + e]], 1.0f);
}

// ---------- node encoder + h0@W_gcn + dinv + hg init (self-loop + bias) ----------
__global__ __launch_bounds__(256) void k_node(
    const float* __restrict__ x, const float* __restrict__ W_ne,
    const float* __restrict__ b_ne, const float* __restrict__ W_gcn,
    const float* __restrict__ b_gcn, const float* __restrict__ deg,
    float* __restrict__ dinv, float* __restrict__ ht, float* __restrict__ hg) {
  __shared__ float sh[4][H];
  const int lane = threadIdx.x & 63;
  const int wv   = threadIdx.x >> 6;
  const int n    = blockIdx.x * 4 + wv;

  float acc = b_ne[lane];
#pragma unroll
  for (int k = 0; k < 5; ++k) acc = fmaf(x[n * 5 + k], W_ne[k * H + lane], acc);
  acc = fmaxf(acc, 0.0f);
  sh[wv][lane] = acc;
  __syncthreads();

  float hv = 0.0f;
#pragma unroll 8
  for (int k = 0; k < H; ++k) hv = fmaf(sh[wv][k], W_gcn[k * H + lane], hv);

  const float dv = rsqrtf(deg[n]);
  if (lane == 0) dinv[n] = dv;
  ht[n * H + lane] = hv;
  hg[n * H + lane] = fmaf(hv, dv * dv, b_gcn[lane]);
}

// ---------- edge scatter: hg[dst] += ht[src] * dinv[src]*dinv[dst] ----------
__global__ __launch_bounds__(256) void k_scatter(const int* __restrict__ ei,
                                                 const float* __restrict__ dinv,
                                                 const float* __restrict__ ht,
                                                 float* __restrict__ hg) {
  const int lane = threadIdx.x & 63;
  const int wv   = threadIdx.x >> 6;
  const int e    = blockIdx.x * 4 + wv;
  const int s = ei[e], d = ei[NE + e];
  const float nv = dinv[s] * dinv[d];
  atomicAdd(&hg[d * H + lane], ht[s * H + lane] * nv);
}

// ---------- prep: hg (f32) -> hgb (bf16), 4 elems/thread ----------
__global__ __launch_bounds__(256) void k_prep_hgb(const float* __restrict__ hg,
                                                  unsigned short* __restrict__ hgb) {
  const int i = (blockIdx.x * 256 + threadIdx.x) * 4;  // NN*H/4 = 800000 threads
  const float4 v = *(const float4*)(hg + i);
  ushort4 o;
  o.x = f2bf(v.x); o.y = f2bf(v.y); o.z = f2bf(v.z); o.w = f2bf(v.w);
  *(ushort4*)(hgb + i) = o;
}

// ---------- prep: W1 (f32 [192][64]) -> W1t (bf16 [64][200], padded) ----------
__global__ __launch_bounds__(256) void k_prep_w1t(const float* __restrict__ W1,
                                                  unsigned short* __restrict__ W1t) {
  const int t = blockIdx.x * 256 + threadIdx.x;  // 48*256 = 12288 = 192*64
  const int n = t / 192, k = t % 192;
  W1t[n * 200 + k] = f2bf(W1[k * H + n]);
}

// ---------- MFMA edge MLP ----------
__global__ __launch_bounds__(256) void k_mlp_mfma(
    const int* __restrict__ ei, const float* __restrict__ eattr,
    const unsigned short* __restrict__ hgb, const unsigned short* __restrict__ W1t,
    const float* __restrict__ W_ee, const float* __restrict__ b_ee,
    const float* __restrict__ b1, const float* __restrict__ W2,
    const float* __restrict__ b2, float* __restrict__ out) {
  __shared__ unsigned short sB[64 * 200];  // 25.6 KB, [n][k] padded

  {  // cooperative LDS fill: 12800 ushort = 6400 dwords = 25/thread
    const unsigned int* g = (const unsigned int*)W1t;
    unsigned int* s = (unsigned int*)sB;
#pragma unroll
    for (int i = 0; i < 25; ++i) s[threadIdx.x + 256 * i] = g[threadIdx.x + 256 * i];
  }
  __syncthreads();

  const int lane = threadIdx.x & 63;
  const int wv   = threadIdx.x >> 6;
  const int l15  = lane & 15;
  const int l4   = lane >> 4;

  // per-lane constants
  float wee[16], bee[16], w2v[4], b1v[4];
#pragma unroll
  for (int j = 0; j < 8; ++j) {
    wee[j]     = W_ee[l4 * 8 + j];      bee[j]     = b_ee[l4 * 8 + j];
    wee[8 + j] = W_ee[32 + l4 * 8 + j]; bee[8 + j] = b_ee[32 + l4 * 8 + j];
  }
#pragma unroll
  for (int nt = 0; nt < 4; ++nt) {
    w2v[nt] = W2[l15 + 16 * nt];
    b1v[nt] = b1[l15 + 16 * nt];
  }
  const float bias2 = b2[0];

#pragma unroll 1
  for (int t = 0; t < 4; ++t) {
    const int eBase = (blockIdx.x * 16 + wv * 4 + t) * 16;
    const int el = eBase + l15;
    const int s = ei[el], d = ei[NE + el];
    const float ea = eattr[el];

    // A fragments: row = l15 (edge), k = l4*8 + j within each 32-chunk
    const bf16x8 a_s0 = *(const bf16x8*)(hgb + (size_t)s * H + l4 * 8);
    const bf16x8 a_s1 = *(const bf16x8*)(hgb + (size_t)s * H + 32 + l4 * 8);
    const bf16x8 a_d0 = *(const bf16x8*)(hgb + (size_t)d * H + l4 * 8);
    const bf16x8 a_d1 = *(const bf16x8*)(hgb + (size_t)d * H + 32 + l4 * 8);

    bf16x8 ae0, ae1;  // edge-feature block, computed in-register
#pragma unroll
    for (int j = 0; j < 8; ++j) {
      ae0[j] = (short)f2bf(fmaxf(fmaf(ea, wee[j], bee[j]), 0.0f));
      ae1[j] = (short)f2bf(fmaxf(fmaf(ea, wee[8 + j], bee[8 + j]), 0.0f));
    }

    f32x4 acc[4] = {(f32x4)(0.f), (f32x4)(0.f), (f32x4)(0.f), (f32x4)(0.f)};
#pragma unroll
    for (int nt = 0; nt < 4; ++nt) {
      const unsigned short* bp = sB + (l15 + nt * 16) * 200 + l4 * 8;
      acc[nt] = __builtin_amdgcn_mfma_f32_16x16x32_bf16(a_s0, *(const bf16x8*)(bp),        acc[nt], 0, 0, 0);
      acc[nt] = __builtin_amdgcn_mfma_f32_16x16x32_bf16(a_s1, *(const bf16x8*)(bp + 32),   acc[nt], 0, 0, 0);
      acc[nt] = __builtin_amdgcn_mfma_f32_16x16x32_bf16(a_d0, *(const bf16x8*)(bp + 64),   acc[nt], 0, 0, 0);
      acc[nt] = __builtin_amdgcn_mfma_f32_16x16x32_bf16(a_d1, *(const bf16x8*)(bp + 96),   acc[nt], 0, 0, 0);
      acc[nt] = __builtin_amdgcn_mfma_f32_16x16x32_bf16(ae0,  *(const bf16x8*)(bp + 128),  acc[nt], 0, 0, 0);
      acc[nt] = __builtin_amdgcn_mfma_f32_16x16x32_bf16(ae1,  *(const bf16x8*)(bp + 160),  acc[nt], 0, 0, 0);
    }

    // second layer (fp32): D row = l4*4 + r (edge), col = l15 + 16*nt
    float p[4];
#pragma unroll
    for (int r = 0; r < 4; ++r) {
      float sum = 0.0f;
#pragma unroll
      for (int nt = 0; nt < 4; ++nt)
        sum = fmaf(fmaxf(acc[nt][r] + b1v[nt], 0.0f), w2v[nt], sum);
      p[r] = sum;
    }
#pragma unroll
    for (int m = 1; m <= 8; m <<= 1) {
#pragma unroll
      for (int r = 0; r < 4; ++r) p[r] += __shfl_xor(p[r], m);
    }
    if (l15 < 4) out[eBase + l4 * 4 + l15] = p[l15] + bias2;
  }
}

extern "C" void kernel_launch(void* const* d_in, const int* in_sizes, int n_in,
                              void* d_out, int out_size, void* d_ws, size_t ws_size,
                              hipStream_t stream) {
  const float* x     = (const float*)d_in[0];
  const int*   ei    = (const int*)d_in[1];
  const float* eattr = (const float*)d_in[2];
  const float* W_ne  = (const float*)d_in[3];
  const float* b_ne  = (const float*)d_in[4];
  const float* W_ee  = (const float*)d_in[5];
  const float* b_ee  = (const float*)d_in[6];
  const float* W_gcn = (const float*)d_in[7];
  const float* b_gcn = (const float*)d_in[8];
  const float* W1    = (const float*)d_in[9];
  const float* b1    = (const float*)d_in[10];
  const float* W2    = (const float*)d_in[11];
  const float* b2    = (const float*)d_in[12];
  float* out = (float*)d_out;

  float* ws   = (float*)d_ws;
  float* ht   = ws;                         // NN*H f32 (dead after k_scatter)
  float* hg   = ws + (size_t)NN * H;        // NN*H f32
  float* deg  = ws + (size_t)2 * NN * H;    // NN f32
  float* dinv = deg + NN;                   // NN f32
  unsigned short* hgb = (unsigned short*)ws;            // reuses ht space (bf16 NN*H)
  unsigned short* W1t = (unsigned short*)(dinv + NN);   // 64*200 bf16

  k_deg_init<<<(NN + 255) / 256, 256, 0, stream>>>(deg);
  k_deg<<<NE / 256, 256, 0, stream>>>(ei, deg);
  k_prep_w1t<<<48, 256, 0, stream>>>(W1, W1t);
  k_node<<<NN / 4, 256, 0, stream>>>(x, W_ne, b_ne, W_gcn, b_gcn, deg, dinv, ht, hg);
  k_scatter<<<NE / 4, 256, 0, stream>>>(ei, dinv, ht, hg);
  k_prep_hgb<<<NN * H / 4 / 256, 256, 0, stream>>>(hg, hgb);
  k_mlp_mfma<<<NE / 256, 256, 0, stream>>>(ei, eattr, hgb, W1t, W_ee, b_ee, b1, W2, b2, out);
}